// Round 1
// baseline (1919.544 us; speedup 1.0000x reference)
//
#include <hip/hip_runtime.h>

#define Bb 2
#define Nn 50000
#define Ee 512000
#define DE 128
#define HH 256
#define DO 128
#define TILES 782  // ceil(50000/64)

typedef __attribute__((ext_vector_type(8))) short short8;
typedef __attribute__((ext_vector_type(4))) float f32x4;

// f32 -> bf16 round-to-nearest-even (data has no NaN/Inf)
static __device__ __forceinline__ unsigned short f2bf(float f) {
  union { float f; unsigned int u; } x; x.f = f;
  return (unsigned short)((x.u + 0x7FFFu + ((x.u >> 16) & 1u)) >> 16);
}

// Pre-convert W1 [256,256] and W2 [256,128] (f32, row-major [k][n]) into
// bf16 MFMA B-fragment order: frag(ct,ks): lane l holds col=ct*16+(l&15),
// k = ks*32+(l>>4)*8+j, j=0..7 contiguous -> one dwordx4 per fragment load.
__global__ void wconv_kernel(const float* __restrict__ W1, const float* __restrict__ W2,
                             unsigned short* __restrict__ w1f, unsigned short* __restrict__ w2f) {
  int t = blockIdx.x * 256 + threadIdx.x;
  if (t < 16 * 8 * 64) {
    int lane = t & 63, ks = (t >> 6) & 7, ct = t >> 9;
    int col = ct * 16 + (lane & 15);
    int k0 = ks * 32 + (lane >> 4) * 8;
    for (int j = 0; j < 8; ++j)
      w1f[t * 8 + j] = f2bf(W1[(k0 + j) * HH + col]);
  }
  if (t < 8 * 8 * 64) {
    int lane = t & 63, ks = (t >> 6) & 7, ct = t >> 9;
    int col = ct * 16 + (lane & 15);
    int k0 = ks * 32 + (lane >> 4) * 8;
    for (int j = 0; j < 8; ++j)
      w2f[t * 8 + j] = f2bf(W2[(k0 + j) * DO + col]);
  }
}

// Scatter-add edge features onto receiver nodes. Thread per (b,e,d4) float4.
__global__ void scatter_kernel(const float* __restrict__ edge, const int* __restrict__ recv,
                               float* __restrict__ agg) {
  const long total = (long)Bb * Ee * (DE / 4);
  const long stride = (long)gridDim.x * blockDim.x;
  for (long i = (long)blockIdx.x * blockDim.x + threadIdx.x; i < total; i += stride) {
    int d4 = (int)(i & 31);
    long be = i >> 5;
    int b = (be >= Ee) ? 1 : 0;
    int e = (int)(be - (long)b * Ee);
    float4 v = reinterpret_cast<const float4*>(edge)[i];
    int r = recv[(long)b * Ee + e];
    float* dst = agg + ((long)b * Nn + r) * DE + d4 * 4;
    unsafeAtomicAdd(dst + 0, v.x);
    unsafeAtomicAdd(dst + 1, v.y);
    unsafeAtomicAdd(dst + 2, v.z);
    unsafeAtomicAdd(dst + 3, v.w);
  }
}

// Fused MLP: per block, 64 nodes. vtin=[agg|node] bf16 in LDS (swizzled),
// GEMM1 (K=256,N=256) -> relu -> h in LDS -> GEMM2 (K=256,N=128) -> out f32.
// 4 waves; wave w owns rows w*16..w*16+15. B-operands from pre-fragmented ws.
__global__ __launch_bounds__(256, 2) void mlp_kernel(
    const float* __restrict__ agg, const float* __restrict__ node,
    const unsigned short* __restrict__ w1f, const unsigned short* __restrict__ w2f,
    const float* __restrict__ b1, const float* __restrict__ b2,
    float* __restrict__ out) {
  __shared__ __align__(16) char lds[64 * 512];  // 64 rows x 256 cols bf16
  const int tid = threadIdx.x;
  const int lane = tid & 63;
  const int wv = tid >> 6;
  const int blk = blockIdx.x;
  const int b = blk / TILES;
  const int tile = blk - b * TILES;
  const int row0 = tile * 64;
  const int rows = min(64, Nn - row0);

  // ---- stage vtin: each wave writes one full row per ii (coalesced) ----
  for (int ii = 0; ii < 16; ++ii) {
    int idx = ii * 256 + tid;
    int row = idx >> 6;
    int c4 = idx & 63;  // float4 column index (0..63 -> col c4*4)
    float4 v = make_float4(0.f, 0.f, 0.f, 0.f);
    if (row < rows) {
      long g = (long)b * Nn + row0 + row;
      if (c4 < 32) v = reinterpret_cast<const float4*>(agg)[g * 32 + c4];
      else         v = reinterpret_cast<const float4*>(node)[g * 32 + (c4 - 32)];
    }
    ushort4 p;
    p.x = f2bf(v.x); p.y = f2bf(v.y); p.z = f2bf(v.z); p.w = f2bf(v.w);
    int byte = row * 512 + ((c4 * 8) ^ ((row & 7) << 4));  // XOR swizzle
    *reinterpret_cast<ushort4*>(&lds[byte]) = p;
  }
  __syncthreads();

  // ---- GEMM1: h = relu(vtin @ W1 + b1) ----
  f32x4 acc[16];
#pragma unroll
  for (int ct = 0; ct < 16; ++ct) acc[ct] = (f32x4){0.f, 0.f, 0.f, 0.f};
  const int arow = wv * 16 + (lane & 15);
  const int abase = arow * 512;
  const int aswz = (arow & 7) << 4;
  const int koff = (lane >> 4) * 16;
#pragma unroll
  for (int ks = 0; ks < 8; ++ks) {
    short8 a = *reinterpret_cast<const short8*>(&lds[abase + ((ks * 64 + koff) ^ aswz)]);
#pragma unroll
    for (int ct = 0; ct < 16; ++ct) {
      short8 bf = *reinterpret_cast<const short8*>(w1f + ((ct * 8 + ks) * 64 + lane) * 8);
      acc[ct] = __builtin_amdgcn_mfma_f32_16x16x32_bf16(a, bf, acc[ct], 0, 0, 0);
    }
  }
  __syncthreads();  // all waves done reading vtin before overwrite

  // ---- bias + relu, write h (bf16, swizzled) ----
  {
    const int colb = lane & 15;
    const int rb = wv * 16 + (lane >> 4) * 4;
#pragma unroll
    for (int ct = 0; ct < 16; ++ct) {
      float bias = b1[ct * 16 + colb];
#pragma unroll
      for (int j = 0; j < 4; ++j) {
        float hv = acc[ct][j] + bias;
        hv = hv > 0.f ? hv : 0.f;
        int row = rb + j;
        int byte = row * 512 + (((ct * 16 + colb) * 2) ^ ((row & 7) << 4));
        *reinterpret_cast<unsigned short*>(&lds[byte]) = f2bf(hv);
      }
    }
  }
  __syncthreads();

  // ---- GEMM2: out = h @ W2 + b2 ----
  f32x4 acc2[8];
#pragma unroll
  for (int ct = 0; ct < 8; ++ct) acc2[ct] = (f32x4){0.f, 0.f, 0.f, 0.f};
#pragma unroll
  for (int ks = 0; ks < 8; ++ks) {
    short8 a = *reinterpret_cast<const short8*>(&lds[abase + ((ks * 64 + koff) ^ aswz)]);
#pragma unroll
    for (int ct = 0; ct < 8; ++ct) {
      short8 bf = *reinterpret_cast<const short8*>(w2f + ((ct * 8 + ks) * 64 + lane) * 8);
      acc2[ct] = __builtin_amdgcn_mfma_f32_16x16x32_bf16(a, bf, acc2[ct], 0, 0, 0);
    }
  }
  {
    const int colb = lane & 15;
    const int rb = wv * 16 + (lane >> 4) * 4;
#pragma unroll
    for (int ct = 0; ct < 8; ++ct) {
      float bias = b2[ct * 16 + colb];
#pragma unroll
      for (int j = 0; j < 4; ++j) {
        int r = rb + j;
        if (r < rows)
          out[((long)b * Nn + row0 + r) * DO + ct * 16 + colb] = acc2[ct][j] + bias;
      }
    }
  }
}

extern "C" void kernel_launch(void* const* d_in, const int* in_sizes, int n_in,
                              void* d_out, int out_size, void* d_ws, size_t ws_size,
                              hipStream_t stream) {
  const float* edge = (const float*)d_in[0];
  const float* node = (const float*)d_in[1];
  const float* W1   = (const float*)d_in[2];
  const float* b1   = (const float*)d_in[3];
  const float* W2   = (const float*)d_in[4];
  const float* b2   = (const float*)d_in[5];
  const int*   recv = (const int*)d_in[6];
  float* out = (float*)d_out;

  char* ws = (char*)d_ws;
  float* agg = (float*)ws;                                      // 51,200,000 B
  unsigned short* w1f = (unsigned short*)(ws + 51200000);       //    131,072 B
  unsigned short* w2f = (unsigned short*)(ws + 51200000 + 131072);  // 65,536 B

  hipMemsetAsync(agg, 0, (size_t)Bb * Nn * DE * sizeof(float), stream);
  wconv_kernel<<<32, 256, 0, stream>>>(W1, W2, w1f, w2f);
  scatter_kernel<<<4096, 256, 0, stream>>>(edge, recv, agg);
  mlp_kernel<<<Bb * TILES, 256, 0, stream>>>(agg, node, w1f, w2f, b1, b2, out);
}

// Round 2
// 456.032 us; speedup vs baseline: 4.2092x; 4.2092x over previous
//
#include <hip/hip_runtime.h>

#define Bb 2
#define Nn 50000
#define Ee 512000
#define DE 128
#define HH 256
#define DO 128
#define TILES 782  // ceil(50000/64)
#define CAP 48     // per-node edge-list capacity (mean degree 10.24; overflow -> atomic fallback)

typedef __attribute__((ext_vector_type(8))) short short8;
typedef __attribute__((ext_vector_type(4))) float f32x4;

// f32 -> bf16 round-to-nearest-even (data has no NaN/Inf)
static __device__ __forceinline__ unsigned short f2bf(float f) {
  union { float f; unsigned int u; } x; x.f = f;
  return (unsigned short)((x.u + 0x7FFFu + ((x.u >> 16) & 1u)) >> 16);
}

// Pre-convert W1 [256,256] and W2 [256,128] (f32, row-major [k][n]) into
// bf16 MFMA B-fragment order: frag(ct,ks): lane l holds col=ct*16+(l&15),
// k = ks*32+(l>>4)*8+j, j=0..7 contiguous -> one dwordx4 per fragment load.
__global__ void wconv_kernel(const float* __restrict__ W1, const float* __restrict__ W2,
                             unsigned short* __restrict__ w1f, unsigned short* __restrict__ w2f) {
  int t = blockIdx.x * 256 + threadIdx.x;
  if (t < 16 * 8 * 64) {
    int lane = t & 63, ks = (t >> 6) & 7, ct = t >> 9;
    int col = ct * 16 + (lane & 15);
    int k0 = ks * 32 + (lane >> 4) * 8;
    for (int j = 0; j < 8; ++j)
      w1f[t * 8 + j] = f2bf(W1[(k0 + j) * HH + col]);
  }
  if (t < 8 * 8 * 64) {
    int lane = t & 63, ks = (t >> 6) & 7, ct = t >> 9;
    int col = ct * 16 + (lane & 15);
    int k0 = ks * 32 + (lane >> 4) * 8;
    for (int j = 0; j < 8; ++j)
      w2f[t * 8 + j] = f2bf(W2[(k0 + j) * DO + col]);
  }
}

// Build per-node edge lists: one int atomic per edge. Overflow (degree > CAP,
// probability ~0 for Poisson(10.24)) falls back to direct f32 atomics into agg.
__global__ void fill_kernel(const int* __restrict__ recv, int* __restrict__ cnt,
                            int* __restrict__ ids, const float* __restrict__ edge,
                            float* __restrict__ agg) {
  long i = (long)blockIdx.x * 256 + threadIdx.x;
  if (i >= (long)Bb * Ee) return;
  int b = (i >= Ee) ? 1 : 0;
  int e = (int)(i - (long)b * Ee);
  int r = recv[i];
  int node = b * Nn + r;
  int pos = atomicAdd(&cnt[node], 1);
  if (pos < CAP) {
    ids[(long)node * CAP + pos] = e;
  } else {  // ~never taken; keeps correctness unconditional
    const float* src = edge + ((long)b * Ee + e) * DE;
    float* dst = agg + (long)node * DE;
    for (int d = 0; d < DE; ++d) unsafeAtomicAdd(dst + d, src[d]);
  }
}

// Gather-sum: one wave per node; lane l owns cols {2l, 2l+1}. Each edge row is
// one coalesced 512B read; agg written exactly once (plus overflow base).
__global__ __launch_bounds__(256) void gather_kernel(
    const float* __restrict__ edge, const int* __restrict__ cnt,
    const int* __restrict__ ids, float* __restrict__ agg) {
  int node = blockIdx.x * 4 + (threadIdx.x >> 6);
  if (node >= Bb * Nn) return;
  int lane = threadIdx.x & 63;
  int b = (node >= Nn) ? 1 : 0;
  int deg = min(cnt[node], CAP);
  const int* myids = ids + (long)node * CAP;
  float2 acc = reinterpret_cast<const float2*>(agg)[(long)node * 64 + lane];  // overflow contributions
  for (int i = 0; i < deg; ++i) {
    int e = myids[i];
    float2 v = reinterpret_cast<const float2*>(edge + ((long)b * Ee + e) * DE)[lane];
    acc.x += v.x;
    acc.y += v.y;
  }
  reinterpret_cast<float2*>(agg)[(long)node * 64 + lane] = acc;
}

// Legacy atomic scatter (fallback if ws too small for edge lists).
__global__ void scatter_kernel(const float* __restrict__ edge, const int* __restrict__ recv,
                               float* __restrict__ agg) {
  const long total = (long)Bb * Ee * (DE / 4);
  const long stride = (long)gridDim.x * blockDim.x;
  for (long i = (long)blockIdx.x * blockDim.x + threadIdx.x; i < total; i += stride) {
    int d4 = (int)(i & 31);
    long be = i >> 5;
    int b = (be >= Ee) ? 1 : 0;
    int e = (int)(be - (long)b * Ee);
    float4 v = reinterpret_cast<const float4*>(edge)[i];
    int r = recv[(long)b * Ee + e];
    float* dst = agg + ((long)b * Nn + r) * DE + d4 * 4;
    unsafeAtomicAdd(dst + 0, v.x);
    unsafeAtomicAdd(dst + 1, v.y);
    unsafeAtomicAdd(dst + 2, v.z);
    unsafeAtomicAdd(dst + 3, v.w);
  }
}

// Fused MLP: per block, 64 nodes. vtin=[agg|node] bf16 in LDS (swizzled),
// GEMM1 (K=256,N=256) -> relu -> h in LDS -> GEMM2 (K=256,N=128) -> out f32.
// 4 waves; wave w owns rows w*16..w*16+15. B-operands from pre-fragmented ws.
__global__ __launch_bounds__(256, 2) void mlp_kernel(
    const float* __restrict__ agg, const float* __restrict__ node,
    const unsigned short* __restrict__ w1f, const unsigned short* __restrict__ w2f,
    const float* __restrict__ b1, const float* __restrict__ b2,
    float* __restrict__ out) {
  __shared__ __align__(16) char lds[64 * 512];  // 64 rows x 256 cols bf16
  const int tid = threadIdx.x;
  const int lane = tid & 63;
  const int wv = tid >> 6;
  const int blk = blockIdx.x;
  const int b = blk / TILES;
  const int tile = blk - b * TILES;
  const int row0 = tile * 64;
  const int rows = min(64, Nn - row0);

  // ---- stage vtin: each wave writes one full row per ii (coalesced) ----
  for (int ii = 0; ii < 16; ++ii) {
    int idx = ii * 256 + tid;
    int row = idx >> 6;
    int c4 = idx & 63;  // float4 column index (0..63 -> col c4*4)
    float4 v = make_float4(0.f, 0.f, 0.f, 0.f);
    if (row < rows) {
      long g = (long)b * Nn + row0 + row;
      if (c4 < 32) v = reinterpret_cast<const float4*>(agg)[g * 32 + c4];
      else         v = reinterpret_cast<const float4*>(node)[g * 32 + (c4 - 32)];
    }
    ushort4 p;
    p.x = f2bf(v.x); p.y = f2bf(v.y); p.z = f2bf(v.z); p.w = f2bf(v.w);
    int byte = row * 512 + ((c4 * 8) ^ ((row & 7) << 4));  // XOR swizzle
    *reinterpret_cast<ushort4*>(&lds[byte]) = p;
  }
  __syncthreads();

  // ---- GEMM1: h = relu(vtin @ W1 + b1) ----
  f32x4 acc[16];
#pragma unroll
  for (int ct = 0; ct < 16; ++ct) acc[ct] = (f32x4){0.f, 0.f, 0.f, 0.f};
  const int arow = wv * 16 + (lane & 15);
  const int abase = arow * 512;
  const int aswz = (arow & 7) << 4;
  const int koff = (lane >> 4) * 16;
#pragma unroll
  for (int ks = 0; ks < 8; ++ks) {
    short8 a = *reinterpret_cast<const short8*>(&lds[abase + ((ks * 64 + koff) ^ aswz)]);
#pragma unroll
    for (int ct = 0; ct < 16; ++ct) {
      short8 bf = *reinterpret_cast<const short8*>(w1f + ((ct * 8 + ks) * 64 + lane) * 8);
      acc[ct] = __builtin_amdgcn_mfma_f32_16x16x32_bf16(a, bf, acc[ct], 0, 0, 0);
    }
  }
  __syncthreads();  // all waves done reading vtin before overwrite

  // ---- bias + relu, write h (bf16, swizzled) ----
  {
    const int colb = lane & 15;
    const int rb = wv * 16 + (lane >> 4) * 4;
#pragma unroll
    for (int ct = 0; ct < 16; ++ct) {
      float bias = b1[ct * 16 + colb];
#pragma unroll
      for (int j = 0; j < 4; ++j) {
        float hv = acc[ct][j] + bias;
        hv = hv > 0.f ? hv : 0.f;
        int row = rb + j;
        int byte = row * 512 + (((ct * 16 + colb) * 2) ^ ((row & 7) << 4));
        *reinterpret_cast<unsigned short*>(&lds[byte]) = f2bf(hv);
      }
    }
  }
  __syncthreads();

  // ---- GEMM2: out = h @ W2 + b2 ----
  f32x4 acc2[8];
#pragma unroll
  for (int ct = 0; ct < 8; ++ct) acc2[ct] = (f32x4){0.f, 0.f, 0.f, 0.f};
#pragma unroll
  for (int ks = 0; ks < 8; ++ks) {
    short8 a = *reinterpret_cast<const short8*>(&lds[abase + ((ks * 64 + koff) ^ aswz)]);
#pragma unroll
    for (int ct = 0; ct < 8; ++ct) {
      short8 bf = *reinterpret_cast<const short8*>(w2f + ((ct * 8 + ks) * 64 + lane) * 8);
      acc2[ct] = __builtin_amdgcn_mfma_f32_16x16x32_bf16(a, bf, acc2[ct], 0, 0, 0);
    }
  }
  {
    const int colb = lane & 15;
    const int rb = wv * 16 + (lane >> 4) * 4;
#pragma unroll
    for (int ct = 0; ct < 8; ++ct) {
      float bias = b2[ct * 16 + colb];
#pragma unroll
      for (int j = 0; j < 4; ++j) {
        int r = rb + j;
        if (r < rows)
          out[((long)b * Nn + row0 + r) * DO + ct * 16 + colb] = acc2[ct][j] + bias;
      }
    }
  }
}

extern "C" void kernel_launch(void* const* d_in, const int* in_sizes, int n_in,
                              void* d_out, int out_size, void* d_ws, size_t ws_size,
                              hipStream_t stream) {
  const float* edge = (const float*)d_in[0];
  const float* node = (const float*)d_in[1];
  const float* W1   = (const float*)d_in[2];
  const float* b1   = (const float*)d_in[3];
  const float* W2   = (const float*)d_in[4];
  const float* b2   = (const float*)d_in[5];
  const int*   recv = (const int*)d_in[6];
  float* out = (float*)d_out;

  char* ws = (char*)d_ws;
  const size_t aggB  = (size_t)Bb * Nn * DE * sizeof(float);  // 51,200,000
  float* agg = (float*)ws;
  unsigned short* w1f = (unsigned short*)(ws + aggB);              // 131,072 B
  unsigned short* w2f = (unsigned short*)(ws + aggB + 131072);     //  65,536 B
  int* cnt = (int*)(ws + aggB + 131072 + 65536);                   // 400,000 B
  int* ids = (int*)(ws + aggB + 131072 + 65536 + 400000);          // Bb*Nn*CAP*4 = 19,200,000 B
  const size_t needed = aggB + 131072 + 65536 + 400000 + (size_t)Bb * Nn * CAP * 4;

  hipMemsetAsync(agg, 0, aggB, stream);
  wconv_kernel<<<32, 256, 0, stream>>>(W1, W2, w1f, w2f);

  if (ws_size >= needed) {
    hipMemsetAsync(cnt, 0, (size_t)Bb * Nn * 4, stream);
    fill_kernel<<<(Bb * Ee + 255) / 256, 256, 0, stream>>>(recv, cnt, ids, edge, agg);
    gather_kernel<<<(Bb * Nn + 3) / 4, 256, 0, stream>>>(edge, cnt, ids, agg);
  } else {
    scatter_kernel<<<4096, 256, 0, stream>>>(edge, recv, agg);
  }
  mlp_kernel<<<Bb * TILES, 256, 0, stream>>>(agg, node, w1f, w2f, b1, b2, out);
}

// Round 4
// 425.104 us; speedup vs baseline: 4.5155x; 1.0728x over previous
//
#include <hip/hip_runtime.h>

#define Bb 2
#define Nn 50000
#define Ee 512000
#define DE 128
#define HH 256
#define DO 128
#define TILES 782        // ceil(50000/64)
#define CAP 48           // per-node edge-list capacity (Poisson(10.24) max deg ~31)
#define NCNT (Bb * Nn)   // 100,000 nodes; cnt[NCNT] is the spill counter
#define SPILL_MAX (Bb * Ee)

typedef __attribute__((ext_vector_type(8))) short short8;
typedef __attribute__((ext_vector_type(4))) float f32x4;

#define ATOMIC_ST(p, v) __hip_atomic_store((p), (v), __ATOMIC_RELAXED, __HIP_MEMORY_SCOPE_AGENT)
#define ATOMIC_LD(p) __hip_atomic_load((p), __ATOMIC_RELAXED, __HIP_MEMORY_SCOPE_AGENT)

// f32 -> bf16 round-to-nearest-even (data has no NaN/Inf)
static __device__ __forceinline__ unsigned short f2bf(float f) {
  union { float f; unsigned int u; } x; x.f = f;
  return (unsigned short)((x.u + 0x7FFFu + ((x.u >> 16) & 1u)) >> 16);
}

// Pre-convert W1 [256,256] and W2 [256,128] (f32, row-major [k][n]) into
// bf16 MFMA B-fragment order: frag(ct,ks): lane l holds col=ct*16+(l&15),
// k = ks*32+(l>>4)*8+j, j=0..7 contiguous -> one dwordx4 per fragment load.
__global__ void wconv_kernel(const float* __restrict__ W1, const float* __restrict__ W2,
                             unsigned short* __restrict__ w1f, unsigned short* __restrict__ w2f) {
  int t = blockIdx.x * 256 + threadIdx.x;
  if (t < 16 * 8 * 64) {
    int lane = t & 63, ks = (t >> 6) & 7, ct = t >> 9;
    int col = ct * 16 + (lane & 15);
    int k0 = ks * 32 + (lane >> 4) * 8;
    for (int j = 0; j < 8; ++j)
      w1f[t * 8 + j] = f2bf(W1[(k0 + j) * HH + col]);
  }
  if (t < 8 * 8 * 64) {
    int lane = t & 63, ks = (t >> 6) & 7, ct = t >> 9;
    int col = ct * 16 + (lane & 15);
    int k0 = ks * 32 + (lane >> 4) * 8;
    for (int j = 0; j < 8; ++j)
      w2f[t * 8 + j] = f2bf(W2[(k0 + j) * DO + col]);
  }
}

// Zero cnt[0..NCNT] (incl. spill counter) with AGENT-scope atomic stores so the
// zeros land at the device coherence point (round-3 post-mortem: plain-stored
// zeros were not reliably observed by later kernels' atomics during graph replay).
__global__ void zero_cnt_kernel(int* __restrict__ cnt) {
  int i = blockIdx.x * 256 + threadIdx.x;
  if (i <= NCNT) ATOMIC_ST(&cnt[i], 0);
}

// Build per-node edge lists: one int atomic per edge. ids entries use
// agent-scope stores; overflow (deg > CAP, ~impossible) goes to a spill list.
__global__ void fill_kernel(const int* __restrict__ recv, int* __restrict__ cnt,
                            int* __restrict__ ids, int* __restrict__ spill) {
  int i = blockIdx.x * 256 + threadIdx.x;  // grid sized to exactly Bb*Ee
  if (i >= Bb * Ee) return;
  int b = (i >= Ee) ? 1 : 0;
  int node = b * Nn + recv[i];
  int pos = atomicAdd(&cnt[node], 1);
  if (pos < CAP) {
    ATOMIC_ST(&ids[(long)node * CAP + pos], i);  // store GLOBAL edge index
  } else {
    int s = atomicAdd(&cnt[NCNT], 1);
    if (s < SPILL_MAX) ATOMIC_ST(&spill[s], i);
  }
}

// Gather-sum: one wave per node; lane l owns cols {2l, 2l+1}. acc starts at 0
// and agg is written unconditionally -> agg never read-before-write, no zeroing.
__global__ __launch_bounds__(256) void gather_kernel(
    const float* __restrict__ edge, const int* __restrict__ cnt,
    const int* __restrict__ ids, float* __restrict__ agg) {
  int node = blockIdx.x * 4 + (threadIdx.x >> 6);
  if (node >= NCNT) return;
  int lane = threadIdx.x & 63;
  int deg = min(ATOMIC_LD((int*)&cnt[node]), CAP);
  const int* myids = ids + (long)node * CAP;
  float2 acc = make_float2(0.f, 0.f);
  for (int i = 0; i < deg; ++i) {
    int e = ATOMIC_LD((int*)&myids[i]);
    float2 v = reinterpret_cast<const float2*>(edge)[(long)e * 64 + lane];
    acc.x += v.x;
    acc.y += v.y;
  }
  reinterpret_cast<float2*>(agg)[(long)node * 64 + lane] = acc;
}

// Apply spill-list edges (normally zero of them) onto agg with f32 atomics.
__global__ void spill_kernel(const float* __restrict__ edge, const int* __restrict__ recv,
                             const int* __restrict__ cnt, const int* __restrict__ spill,
                             float* __restrict__ agg) {
  int n = min(ATOMIC_LD((int*)&cnt[NCNT]), SPILL_MAX);
  int wave = (blockIdx.x * 256 + threadIdx.x) >> 6;
  int lane = threadIdx.x & 63;
  int nwaves = gridDim.x * 4;
  for (int s = wave; s < n; s += nwaves) {
    int i = ATOMIC_LD((int*)&spill[s]);
    int b = (i >= Ee) ? 1 : 0;
    int node = b * Nn + recv[i];
    float2 v = reinterpret_cast<const float2*>(edge)[(long)i * 64 + lane];
    unsafeAtomicAdd(&agg[(long)node * DE + lane * 2], v.x);
    unsafeAtomicAdd(&agg[(long)node * DE + lane * 2 + 1], v.y);
  }
}

// Fused MLP: per block, 64 nodes. vtin=[agg|node] bf16 in LDS (swizzled),
// GEMM1 (K=256,N=256) -> relu -> h in LDS -> GEMM2 (K=256,N=128) -> out f32.
// 4 waves; wave w owns rows w*16..w*16+15. B-operands from pre-fragmented ws.
__global__ __launch_bounds__(256, 2) void mlp_kernel(
    const float* __restrict__ agg, const float* __restrict__ node,
    const unsigned short* __restrict__ w1f, const unsigned short* __restrict__ w2f,
    const float* __restrict__ b1, const float* __restrict__ b2,
    float* __restrict__ out) {
  __shared__ __align__(16) char lds[64 * 512];  // 64 rows x 256 cols bf16
  const int tid = threadIdx.x;
  const int lane = tid & 63;
  const int wv = tid >> 6;
  const int blk = blockIdx.x;
  const int b = blk / TILES;
  const int tile = blk - b * TILES;
  const int row0 = tile * 64;
  const int rows = min(64, Nn - row0);

  // ---- stage vtin: each wave writes one full row per ii (coalesced) ----
  for (int ii = 0; ii < 16; ++ii) {
    int idx = ii * 256 + tid;
    int row = idx >> 6;
    int c4 = idx & 63;  // float4 column index (0..63 -> col c4*4)
    float4 v = make_float4(0.f, 0.f, 0.f, 0.f);
    if (row < rows) {
      long g = (long)b * Nn + row0 + row;
      if (c4 < 32) v = reinterpret_cast<const float4*>(agg)[g * 32 + c4];
      else         v = reinterpret_cast<const float4*>(node)[g * 32 + (c4 - 32)];
    }
    ushort4 p;
    p.x = f2bf(v.x); p.y = f2bf(v.y); p.z = f2bf(v.z); p.w = f2bf(v.w);
    int byte = row * 512 + ((c4 * 8) ^ ((row & 7) << 4));  // XOR swizzle
    *reinterpret_cast<ushort4*>(&lds[byte]) = p;
  }
  __syncthreads();

  // ---- GEMM1: h = relu(vtin @ W1 + b1) ----
  f32x4 acc[16];
#pragma unroll
  for (int ct = 0; ct < 16; ++ct) acc[ct] = (f32x4){0.f, 0.f, 0.f, 0.f};
  const int arow = wv * 16 + (lane & 15);
  const int abase = arow * 512;
  const int aswz = (arow & 7) << 4;
  const int koff = (lane >> 4) * 16;
#pragma unroll
  for (int ks = 0; ks < 8; ++ks) {
    short8 a = *reinterpret_cast<const short8*>(&lds[abase + ((ks * 64 + koff) ^ aswz)]);
#pragma unroll
    for (int ct = 0; ct < 16; ++ct) {
      short8 bf = *reinterpret_cast<const short8*>(w1f + ((ct * 8 + ks) * 64 + lane) * 8);
      acc[ct] = __builtin_amdgcn_mfma_f32_16x16x32_bf16(a, bf, acc[ct], 0, 0, 0);
    }
  }
  __syncthreads();  // all waves done reading vtin before overwrite

  // ---- bias + relu, write h (bf16, swizzled) ----
  {
    const int colb = lane & 15;
    const int rb = wv * 16 + (lane >> 4) * 4;
#pragma unroll
    for (int ct = 0; ct < 16; ++ct) {
      float bias = b1[ct * 16 + colb];
#pragma unroll
      for (int j = 0; j < 4; ++j) {
        float hv = acc[ct][j] + bias;
        hv = hv > 0.f ? hv : 0.f;
        int row = rb + j;
        int byte = row * 512 + (((ct * 16 + colb) * 2) ^ ((row & 7) << 4));
        *reinterpret_cast<unsigned short*>(&lds[byte]) = f2bf(hv);
      }
    }
  }
  __syncthreads();

  // ---- GEMM2: out = h @ W2 + b2 ----
  f32x4 acc2[8];
#pragma unroll
  for (int ct = 0; ct < 8; ++ct) acc2[ct] = (f32x4){0.f, 0.f, 0.f, 0.f};
#pragma unroll
  for (int ks = 0; ks < 8; ++ks) {
    short8 a = *reinterpret_cast<const short8*>(&lds[abase + ((ks * 64 + koff) ^ aswz)]);
#pragma unroll
    for (int ct = 0; ct < 8; ++ct) {
      short8 bf = *reinterpret_cast<const short8*>(w2f + ((ct * 8 + ks) * 64 + lane) * 8);
      acc2[ct] = __builtin_amdgcn_mfma_f32_16x16x32_bf16(a, bf, acc2[ct], 0, 0, 0);
    }
  }
  {
    const int colb = lane & 15;
    const int rb = wv * 16 + (lane >> 4) * 4;
#pragma unroll
    for (int ct = 0; ct < 8; ++ct) {
      float bias = b2[ct * 16 + colb];
#pragma unroll
      for (int j = 0; j < 4; ++j) {
        int r = rb + j;
        if (r < rows)
          out[((long)b * Nn + row0 + r) * DO + ct * 16 + colb] = acc2[ct][j] + bias;
      }
    }
  }
}

// ---- fallback path (ws too small for lists; not expected to run) ----
__global__ void zero_agg_kernel(float* __restrict__ agg) {
  int i = blockIdx.x * 256 + threadIdx.x;
  int stride = gridDim.x * 256;
  for (; i < Bb * Nn * DE; i += stride) ATOMIC_ST((int*)&agg[i], 0);
}
__global__ void scatter_kernel(const float* __restrict__ edge, const int* __restrict__ recv,
                               float* __restrict__ agg) {
  const long total = (long)Bb * Ee * (DE / 4);
  const long stride = (long)gridDim.x * blockDim.x;
  for (long i = (long)blockIdx.x * blockDim.x + threadIdx.x; i < total; i += stride) {
    int d4 = (int)(i & 31);
    long be = i >> 5;
    int b = (be >= Ee) ? 1 : 0;
    int e = (int)(be - (long)b * Ee);
    float4 v = reinterpret_cast<const float4*>(edge)[i];
    int r = recv[(long)b * Ee + e];
    float* dst = agg + ((long)b * Nn + r) * DE + d4 * 4;
    unsafeAtomicAdd(dst + 0, v.x);
    unsafeAtomicAdd(dst + 1, v.y);
    unsafeAtomicAdd(dst + 2, v.z);
    unsafeAtomicAdd(dst + 3, v.w);
  }
}

extern "C" void kernel_launch(void* const* d_in, const int* in_sizes, int n_in,
                              void* d_out, int out_size, void* d_ws, size_t ws_size,
                              hipStream_t stream) {
  const float* edge = (const float*)d_in[0];
  const float* node = (const float*)d_in[1];
  const float* W1   = (const float*)d_in[2];
  const float* b1   = (const float*)d_in[3];
  const float* W2   = (const float*)d_in[4];
  const float* b2   = (const float*)d_in[5];
  const int*   recv = (const int*)d_in[6];
  float* out = (float*)d_out;

  char* ws = (char*)d_ws;
  const size_t aggB = (size_t)Bb * Nn * DE * sizeof(float);      // 51,200,000
  float* agg = (float*)ws;
  unsigned short* w1f = (unsigned short*)(ws + aggB);            // 131,072 B
  unsigned short* w2f = (unsigned short*)(ws + aggB + 131072);   //  65,536 B
  int* cnt   = (int*)(ws + aggB + 131072 + 65536);               // (NCNT+1)*4 -> pad 400,016
  int* spill = (int*)(ws + aggB + 131072 + 65536 + 400016);      // SPILL_MAX*4 = 4,096,000
  int* ids   = (int*)(ws + aggB + 131072 + 65536 + 400016 + 4096000);  // 19,200,000
  const size_t needed = aggB + 131072 + 65536 + 400016 + 4096000 + (size_t)NCNT * CAP * 4;

  wconv_kernel<<<32, 256, 0, stream>>>(W1, W2, w1f, w2f);

  if (ws_size >= needed) {
    zero_cnt_kernel<<<(NCNT + 256) / 256, 256, 0, stream>>>(cnt);
    fill_kernel<<<Bb * Ee / 256, 256, 0, stream>>>(recv, cnt, ids, spill);
    gather_kernel<<<(NCNT + 3) / 4, 256, 0, stream>>>(edge, cnt, ids, agg);
    spill_kernel<<<64, 256, 0, stream>>>(edge, recv, cnt, spill, agg);
  } else {
    zero_agg_kernel<<<2048, 256, 0, stream>>>(agg);
    scatter_kernel<<<4096, 256, 0, stream>>>(edge, recv, agg);
  }
  mlp_kernel<<<Bb * TILES, 256, 0, stream>>>(agg, node, w1f, w2f, b1, b2, out);
}